// Round 4
// baseline (6082.703 us; speedup 1.0000x reference)
//
#include <hip/hip_runtime.h>
#include <cstdint>
#include <cstddef>

// ---------------- problem constants ----------------
#define B_    64
#define L_    256
#define E_    768
#define H_    12
#define DH_   64
#define D_    8
#define FF_   3072
#define QKV3_ 2304
#define M_    (B_*L_)   // 16384 token rows

typedef _Float16 f16;
typedef f16   f16x8  __attribute__((ext_vector_type(8)));
typedef float f32x4  __attribute__((ext_vector_type(4)));

// async global->LDS DMA, 16B per lane; LDS dest must be wave-uniform base + lane*16
__device__ __forceinline__ void gl_lds16(const void* g, void* l){
    __builtin_amdgcn_global_load_lds(
        (const __attribute__((address_space(1))) void*)g,
        (__attribute__((address_space(3))) void*)l, 16, 0, 0);
}

// ---------------- sentinel (ws too small diagnostic) ----------------
__global__ void sentinel_kernel(float* out, int n){
    int i = blockIdx.x*64 + threadIdx.x;
    if (i < n) out[i] = 1.0e6f;
}

// ---------------- embed gather ----------------
__global__ __launch_bounds__(256) void gather_kernel(
    const int* __restrict__ tok, const float* __restrict__ emb, float* __restrict__ e)
{
    const int idx = blockIdx.x*256 + threadIdx.x;
    const int row = idx / E_;
    const int d   = idx - row*E_;
    e[idx] = emb[(size_t)tok[row]*E_ + d];
}

// ---------------- weight transpose -> f16: W (K x N) -> (N x K) ----------------
__global__ void wsplit_kernel(const float* __restrict__ W, f16* __restrict__ Hh, int K, int N)
{
    __shared__ float tile[32][33];
    const int tx = threadIdx.x, ty = threadIdx.y;        // 32 x 8
#pragma unroll
    for (int i2 = 0; i2 < 4; ++i2){
        const int k = blockIdx.y*32 + ty + i2*8;
        const int n = blockIdx.x*32 + tx;
        tile[ty + i2*8][tx] = W[(size_t)k*N + n];
    }
    __syncthreads();
    const int k2 = blockIdx.y*32 + tx;
#pragma unroll
    for (int i2 = 0; i2 < 4; ++i2){
        const int n2 = blockIdx.x*32 + ty + i2*8;
        Hh[(size_t)n2*K + k2] = (f16)tile[tx][ty + i2*8];
    }
}

// ---------------- layernorm over E=768: optional f32 out + optional hi/lo f16 planes ----------------
__global__ __launch_bounds__(256) void ln_kernel(
    const float* __restrict__ x, const float* __restrict__ g, const float* __restrict__ bb,
    float* __restrict__ yF, f16* __restrict__ yH, f16* __restrict__ yL)
{
    __shared__ float red[256];
    const int row = blockIdx.x, tid = threadIdx.x;
    const float* xr = x + (size_t)row*E_;
    float v0 = xr[tid], v1 = xr[tid+256], v2 = xr[tid+512];
    red[tid] = v0 + v1 + v2;
    __syncthreads();
    for (int o = 128; o; o >>= 1){ if (tid < o) red[tid] += red[tid+o]; __syncthreads(); }
    const float mean = red[0] * (1.f/768.f);
    __syncthreads();
    const float d0 = v0-mean, d1 = v1-mean, d2 = v2-mean;
    red[tid] = d0*d0 + d1*d1 + d2*d2;
    __syncthreads();
    for (int o = 128; o; o >>= 1){ if (tid < o) red[tid] += red[tid+o]; __syncthreads(); }
    const float rstd = rsqrtf(red[0]*(1.f/768.f) + 1e-5f);
    const float dv[3] = {d0, d1, d2};
#pragma unroll
    for (int q = 0; q < 3; ++q){
        const int d = tid + q*256;
        const float y = dv[q]*rstd*g[d] + bb[d];
        const size_t idx = (size_t)row*E_ + d;
        if (yF) yF[idx] = y;
        if (yH){
            const f16 hi = (f16)y;
            yH[idx] = hi;
            yL[idx] = (f16)(y - (float)hi);
        }
    }
}

// ---------------- f16 GEMM: 128x128 tile, A via LDS (swizzled), B DIRECT from L2 ----------------
// C = A @ B^T + bias (+epilogue). A: Mn x Kn row-major f16. B^T: Nn x Kn row-major f16.
// R3 post-mortem: 128^2 structure is LDS-PIPE bound (~1130cy/CU-step vs 620cy MFMA).
// Fix: B (weights, 1.2-4.7 MB, reused by all M-blocks -> L2-resident) is loaded
// DIRECTLY global->reg as per-lane f16x8, software-pipelined 1 K-step ahead in a
// statically-indexed fbuf[2][4]. LDS carries only A (gl_lds, 4 buffers, 3-ahead,
// R3-VERIFIED involution swizzle: conflicts=0). New CU-step balance (3 blocks/CU):
// LDS ~850cy < MFMA ~930cy -> MFMA-bound.
// vmcnt (FIFO, 2 A-loads + 4 B-loads per step): steady wait vmcnt(12) forces
// A(st+1)+older done, leaves A(st+2..3), fb(st), fb(st+1) in flight (safe for
// prologue order too); tail 10/8/4. Raw s_barrier (no vmcnt0 drain).
// nsteps divisible by 4 (K=768 -> 24, K=3072 -> 96). LDS 32 KiB.
// MODE 0 (QKV): scatter f16 -> qh/kh [b][h][256][64], vt [b][h][64][256]
// MODE 1 (Wo):  Cf = v + exH+exL (f32)
// MODE 2 (W1):  Cq = (f16)relu(v)
// MODE 3 (W2):  Cf = (pad?0:v) + exH+exL (f32)
template<int MODE>
__global__ __launch_bounds__(256, 3) void gemm_kernel(
    const f16* __restrict__ A, const f16* __restrict__ Bh,
    const float* __restrict__ bias,
    const f16* __restrict__ exH, const f16* __restrict__ exL,
    const unsigned char* __restrict__ pad,
    float* __restrict__ Cf, f16* __restrict__ Cq,
    f16* __restrict__ qh, f16* __restrict__ kh, f16* __restrict__ vt,
    int Mn, int Nn, int Kn)
{
    __shared__ f16 sA[4][128*32];    // 4 x 8KB (A only)
    const int tid = threadIdx.x;
    const int w = tid >> 6, l = tid & 63;
    // ---- XCD-aware swizzle: xcd = flat%8 fixed; within an XCD iterate n fastest ----
    const int nt = gridDim.x;
    const int flat = blockIdx.y * nt + blockIdx.x;
    const int xcd = flat & 7, grp = flat >> 3;
    const int bx = grp % nt;
    const int by = xcd + 8 * (grp / nt);      // gridDim.y = 128 (multiple of 8)
    const int m0 = by * 128, n0 = bx * 128;
    const int waveM = (w & 1) * 64, waveN = (w >> 1) * 64;
    const int fr = l & 15, fq = l >> 4;
    const int kswz = ((fq ^ ((fr >> 1) & 3)) << 3);   // swizzled k-chunk (f16 elems)
    f32x4 acc[4][4] = {};

    // ---- A staging: thread t loads chunks {t, t+256}; chunk q: row=q>>2, pos=q&3
    //      holds global chunk (pos ^ ((row>>1)&3))  [involution; verified R3] ----
    const int r0 = tid >> 2, j0 = tid & 3;
    const int r1 = r0 + 64;
    const int j0s = j0 ^ ((r0 >> 1) & 3);
    const int j1s = j0 ^ ((r1 >> 1) & 3);
    const f16* pa0 = A + (size_t)(m0 + r0) * Kn + j0s*8;
    const f16* pa1 = A + (size_t)(m0 + r1) * Kn + j1s*8;
    const int d0 = tid*8, d1 = tid*8 + 2048;   // linear LDS dests (f16 elems)

    // ---- B direct per-wave fragment pointers (hit L2; reused by all M-blocks) ----
    const f16* pb[4];
#pragma unroll
    for (int n = 0; n < 4; ++n)
        pb[n] = Bh + (size_t)(n0 + waveN + n*16 + fr) * Kn + fq*8;

    f16x8 fbuf[2][4];    // statically-indexed double buffer (rule #20)

#define STAGE_(U, KK) do { \
        const size_t ko_ = (size_t)(KK) * 32; \
        gl_lds16(pa0 + ko_, &sA[U][d0]); \
        gl_lds16(pa1 + ko_, &sA[U][d1]); \
    } while(0)

#define LOADB_(P, KK) do { \
        const size_t ko_ = (size_t)(KK) * 32; \
        _Pragma("unroll") \
        for (int n = 0; n < 4; ++n) \
            fbuf[P][n] = *(const f16x8*)(pb[n] + ko_); \
    } while(0)

#define COMPUTE_(U, P) do { \
        f16x8 fa[4]; \
        _Pragma("unroll") \
        for (int m = 0; m < 4; ++m) \
            fa[m] = *(const f16x8*)&sA[U][(waveM + m*16 + fr)*32 + kswz]; \
        __builtin_amdgcn_s_setprio(1); \
        _Pragma("unroll") \
        for (int m = 0; m < 4; ++m) \
        _Pragma("unroll") \
        for (int n = 0; n < 4; ++n) \
            acc[m][n] = __builtin_amdgcn_mfma_f32_16x16x32_f16(fa[m], fbuf[P][n], acc[m][n], 0,0,0); \
        __builtin_amdgcn_s_setprio(0); \
    } while(0)

#define WAITV12 asm volatile("s_waitcnt vmcnt(12)" ::: "memory")
#define WAITV10 asm volatile("s_waitcnt vmcnt(10)" ::: "memory")
#define WAITV8  asm volatile("s_waitcnt vmcnt(8)"  ::: "memory")
#define WAITV4  asm volatile("s_waitcnt vmcnt(4)"  ::: "memory")
#define BAR_    do { asm volatile("" ::: "memory"); __builtin_amdgcn_s_barrier(); asm volatile("" ::: "memory"); } while(0)

    const int ns = Kn >> 5;          // divisible by 4 for all shapes used here
    STAGE_(0, 0);
    STAGE_(1, 1);
    STAGE_(2, 2);
    LOADB_(0, 0);
    for (int s = 0; s < ns; s += 4){
#pragma unroll
        for (int u = 0; u < 4; ++u){
            const int st = s + u;
            if (st + 3 < ns) STAGE_((u+3)&3, st+3);
            if (st + 1 < ns) LOADB_((u+1)&1, st+1);
            if      (st + 3 < ns) WAITV12;   // forces A(st+1)+older landed
            else if (st + 2 < ns) WAITV10;
            else if (st + 1 < ns) WAITV8;
            else                  WAITV4;
            BAR_;                        // publish sA[u] (all waves counted their loads)
            COMPUTE_(u, u&1);
            BAR_;                        // all waves done reading sA[u]; may overwrite
        }
    }
#undef STAGE_
#undef LOADB_
#undef COMPUTE_
#undef WAITV12
#undef WAITV10
#undef WAITV8
#undef WAITV4
#undef BAR_

    // epilogue: C/D layout col=lane&15, row=(lane>>4)*4+reg [m89/m91-verified]
#pragma unroll
    for (int jt = 0; jt < 4; ++jt){
        const int col = n0 + waveN + jt*16 + fr;
        const float bc = bias[col];
        int which = 0, hh = 0, dd = 0;
        if (MODE == 0){
            which = col / 768;
            const int hc = col - which*768;
            hh = hc >> 6; dd = hc & 63;
        }
#pragma unroll
        for (int it = 0; it < 4; ++it)
#pragma unroll
            for (int rg = 0; rg < 4; ++rg){
                const int row = m0 + waveM + it*16 + fq*4 + rg;
                float v = acc[it][jt][rg] + bc;
                if (MODE == 0){
                    const int bb2 = row >> 8, jj2 = row & 255;
                    const size_t bh = (size_t)bb2 * H_ + hh;
                    if (which == 0)      qh[(bh*256 + jj2)*64 + dd] = (f16)v;
                    else if (which == 1) kh[(bh*256 + jj2)*64 + dd] = (f16)v;
                    else                 vt[(bh*64 + dd)*256 + jj2] = (f16)v;
                } else {
                    const size_t idx = (size_t)row * Nn + col;
                    if (MODE == 1){
                        Cf[idx] = v + (float)exH[idx] + (float)exL[idx];
                    } else if (MODE == 2){
                        Cq[idx] = (f16)fmaxf(v, 0.f);
                    } else {
                        if (pad[row]) v = 0.f;
                        Cf[idx] = v + (float)exH[idx] + (float)exL[idx];
                    }
                }
            }
    }
}

// ---------------- MFMA flash attention: block per (b,h,p); p = 64-q-row quarter ----------------
__global__ __launch_bounds__(256, 4) void attn_kernel(
    const f16* __restrict__ qh, const f16* __restrict__ kh, const f16* __restrict__ vt,
    const float* __restrict__ rpos, const unsigned char* __restrict__ pad,
    const float* __restrict__ mu, const float* __restrict__ ga, const float* __restrict__ wv,
    f16* __restrict__ o)
{
    __shared__ f16 sK[64*72];        // K chunk [j][d], pad 72
    __shared__ f16 sV[64*72];        // Vt chunk [d][j], pad 72
    __shared__ f16 sP[4][16*72];     // per-wave P rows (A-layout), pad 72
    __shared__ float rx[256], ry[256], rz[256], pf[256];

    const int h = blockIdx.x, b = blockIdx.y, p = blockIdx.z;
    const int tid = threadIdx.x, w = tid >> 6, l = tid & 63;
    const int fr = l & 15, fq = l >> 4;
    const float muh = mu[h], gah = ga[h], wh = wv[h];
    const size_t bh = (size_t)b * H_ + h;
    const int rowbase = b * L_;

    rx[tid] = rpos[(size_t)(rowbase+tid)*3 + 0];
    ry[tid] = rpos[(size_t)(rowbase+tid)*3 + 1];
    rz[tid] = rpos[(size_t)(rowbase+tid)*3 + 2];
    pf[tid] = pad[rowbase+tid] ? 1.f : 0.f;

    f16x8 fQ[2];
    {
        const int r = p*64 + w*16 + fr;
        const f16* qp = qh + (bh*256 + r)*64 + fq*8;
        fQ[0] = *(const f16x8*)(qp);
        fQ[1] = *(const f16x8*)(qp + 32);
    }

    float m_[4], l_[4];
    f32x4 oacc[4] = {};
#pragma unroll
    for (int rg = 0; rg < 4; ++rg){ m_[rg] = -3.0e38f; l_[rg] = 0.f; }
    __syncthreads();

    for (int c = 0; c < 4; ++c){     // j-chunks of 64
        __syncthreads();
        {   // stage K chunk + Vt chunk (each 64x64 f16)
            const int e0 = tid*8, e1 = e0 + 2048;
            const int kr0 = e0 >> 6, kd0 = e0 & 63;
            const int kr1 = e1 >> 6, kd1 = e1 & 63;
            *(uint4*)&sK[kr0*72 + kd0] = *(const uint4*)&kh[(bh*256 + c*64 + kr0)*64 + kd0];
            *(uint4*)&sK[kr1*72 + kd1] = *(const uint4*)&kh[(bh*256 + c*64 + kr1)*64 + kd1];
            *(uint4*)&sV[kr0*72 + kd0] = *(const uint4*)&vt[(bh*64 + kr0)*256 + c*64 + kd0];
            *(uint4*)&sV[kr1*72 + kd1] = *(const uint4*)&vt[(bh*64 + kr1)*256 + c*64 + kd1];
        }
        __syncthreads();
        // ---- S = Q K^T ----
        f32x4 sacc[4] = {};
#pragma unroll
        for (int nt = 0; nt < 4; ++nt)
#pragma unroll
            for (int kf = 0; kf < 2; ++kf){
                const f16x8 fb = *(const f16x8*)&sK[(nt*16 + fr)*72 + kf*32 + fq*8];
                sacc[nt] = __builtin_amdgcn_mfma_f32_16x16x32_f16(fQ[kf], fb, sacc[nt], 0,0,0);
            }
        // ---- bias + mask ----
        float sv[4][4];
        float rmax[4] = {-3.0e38f, -3.0e38f, -3.0e38f, -3.0e38f};
        const int ibase = p*64 + w*16 + fq*4;
#pragma unroll
        for (int nt = 0; nt < 4; ++nt){
            const int j = c*64 + nt*16 + fr;
            const float jx = rx[j], jy = ry[j], jz = rz[j], jp = pf[j];
#pragma unroll
            for (int rg = 0; rg < 4; ++rg){
                const int i = ibase + rg;
                const float dx = rx[i]-jx, dy = ry[i]-jy, dz = rz[i]-jz;
                const float dist = sqrtf(dx*dx + dy*dy + dz*dz + 1e-12f);
                const float t = dist - muh;
                float s = sacc[nt][rg]*0.125f + wh*__expf(-gah*t*t);
                if ((j == i) | (pf[i] != 0.f) | (jp != 0.f)) s = -1e9f;
                sv[nt][rg] = s;
                rmax[rg] = fmaxf(rmax[rg], s);
            }
        }
        // ---- online softmax; P -> wave-private LDS (A layout) ----
#pragma unroll
        for (int rg = 0; rg < 4; ++rg){
#pragma unroll
            for (int off = 8; off >= 1; off >>= 1)
                rmax[rg] = fmaxf(rmax[rg], __shfl_xor(rmax[rg], off));
            const float mnew = fmaxf(m_[rg], rmax[rg]);
            const float alpha = __expf(m_[rg] - mnew);
            m_[rg] = mnew;
            l_[rg] *= alpha;
#pragma unroll
            for (int dt = 0; dt < 4; ++dt) oacc[dt][rg] *= alpha;
            float rs = 0.f;
#pragma unroll
            for (int nt = 0; nt < 4; ++nt){
                const float pv = __expf(sv[nt][rg] - mnew);
                sP[w][(fq*4 + rg)*72 + nt*16 + fr] = (f16)pv;
                rs += pv;
            }
#pragma unroll
            for (int off = 8; off >= 1; off >>= 1) rs += __shfl_xor(rs, off);
            l_[rg] += rs;
        }
        // ---- O += P @ V ----
#pragma unroll
        for (int kf = 0; kf < 2; ++kf){
            const f16x8 pa = *(const f16x8*)&sP[w][fr*72 + kf*32 + fq*8];
#pragma unroll
            for (int dt = 0; dt < 4; ++dt){
                const f16x8 vb = *(const f16x8*)&sV[(dt*16 + fr)*72 + kf*32 + fq*8];
                oacc[dt] = __builtin_amdgcn_mfma_f32_16x16x32_f16(pa, vb, oacc[dt], 0,0,0);
            }
        }
    }
    const int rglob = rowbase + p*64 + w*16 + fq*4;
#pragma unroll
    for (int rg = 0; rg < 4; ++rg){
        const float inv = 1.f / l_[rg];
#pragma unroll
        for (int dt = 0; dt < 4; ++dt)
            o[(size_t)(rglob + rg)*E_ + h*64 + dt*16 + fr] = (f16)(oacc[dt][rg]*inv);
    }
}

// ---------------- mean over L per (b, dim) ----------------
__global__ __launch_bounds__(256) void mean_kernel(const float* __restrict__ x, float* __restrict__ m)
{
    const int b = blockIdx.x, tid = threadIdx.x;
    const float* xb = x + (size_t)b*L_*E_;
#pragma unroll
    for (int q = 0; q < 3; ++q){
        const int d = tid + q*256;
        float s = 0.f;
        for (int l2 = 0; l2 < L_; ++l2) s += xb[(size_t)l2*E_ + d];
        m[b*E_ + d] = s * (1.f/(float)L_);
    }
}

// ---------------- final projection ----------------
__global__ __launch_bounds__(256) void out_kernel(
    const float* __restrict__ m, const float* __restrict__ Wout,
    const float* __restrict__ bout, float* __restrict__ out)
{
    __shared__ float red[256];
    const int b = blockIdx.x, tid = threadIdx.x;
    float s = 0.f;
#pragma unroll
    for (int q = 0; q < 3; ++q){ const int d = tid + q*256; s += m[b*E_ + d]*Wout[d]; }
    red[tid] = s;
    __syncthreads();
    for (int o = 128; o; o >>= 1){ if (tid < o) red[tid] += red[tid+o]; __syncthreads(); }
    if (tid == 0) out[b] = red[0] + bout[0];
}

// ---------------- host ----------------
extern "C" void kernel_launch(void* const* d_in, const int* in_sizes, int n_in,
                              void* d_out, int out_size, void* d_ws, size_t ws_size,
                              hipStream_t stream)
{
    const int*            tokens  = (const int*)d_in[0];
    const unsigned char*  padding = (const unsigned char*)d_in[1];
    const float*          rpos    = (const float*)d_in[2];
    const float*          embed   = (const float*)d_in[3];
    const float*          mu      = (const float*)d_in[4];
    const float*          ga      = (const float*)d_in[5];
    const float*          wv      = (const float*)d_in[6];
    const float*          Wqkv    = (const float*)d_in[7];
    const float*          bqkv    = (const float*)d_in[8];
    const float*          Wo      = (const float*)d_in[9];
    const float*          bo      = (const float*)d_in[10];
    const float*          ln1g    = (const float*)d_in[11];
    const float*          ln1b    = (const float*)d_in[12];
    const float*          W1      = (const float*)d_in[13];
    const float*          b1      = (const float*)d_in[14];
    const float*          W2      = (const float*)d_in[15];
    const float*          b2      = (const float*)d_in[16];
    const float*          ln2g    = (const float*)d_in[17];
    const float*          ln2b    = (const float*)d_in[18];
    const float*          lnfg    = (const float*)d_in[19];
    const float*          lnfb    = (const float*)d_in[20];
    const float*          Wout    = (const float*)d_in[21];
    const float*          bout    = (const float*)d_in[22];
    float* out = (float*)d_out;
    (void)in_sizes; (void)n_in;

    char* ws = (char*)d_ws;
    size_t off = 0;
    auto alloc = [&](size_t bytes)->char*{
        char* p = ws + off;
        off += (bytes + 255) & ~(size_t)255;
        return p;
    };
    const size_t PLANE = (size_t)M_*E_;                 // 12.58M elems
    float* e     = (float*)alloc(PLANE*4);              // residual; also s (Wo out) mid-layer
    char*  big   = alloc(PLANE*2*4);                    // qh|kh|vt|o ; later hbuf; later lnf f32
    f16*   actH  = (f16*)alloc(PLANE*2);                // LN planes (hi; GEMM A operand)
    f16*   actL  = (f16*)alloc(PLANE*2);                // LN planes (lo; residual reconstruction)
    f16*   wqh   = (f16*)alloc((size_t)E_*QKV3_*2);
    f16*   woh   = (f16*)alloc((size_t)E_*E_*2);
    f16*   w1h   = (f16*)alloc((size_t)E_*FF_*2);
    f16*   w2h   = (f16*)alloc((size_t)FF_*E_*2);
    float* meanb = (float*)alloc((size_t)B_*E_*4);
    const size_t required = off;

    if (ws_size < required){
        sentinel_kernel<<<dim3((out_size+63)/64), dim3(64), 0, stream>>>(out, out_size);
        return;
    }

    // aliases inside `big` (lifetimes disjoint):
    f16*   qh   = (f16*)big;                 // QKV gemm -> attn
    f16*   kh   = qh + PLANE;
    f16*   vt   = kh + PLANE;
    f16*   ob   = vt + PLANE;                // attn -> Wo gemm
    f16*   hbuf = (f16*)big;                 // W1 -> W2 (after qkv/o dead)
    float* lnfo = (float*)big;               // final LN out (first half)
    float* sbuf = e;                         // Wo-out f32 aliases residual (e dead LN1..MODE3)

    gather_kernel<<<dim3(M_*E_/256), dim3(256), 0, stream>>>(tokens, embed, e);

    for (int i = 0; i < D_; ++i){
        wsplit_kernel<<<dim3(QKV3_/32, E_/32), dim3(32,8), 0, stream>>>(
            Wqkv + (size_t)i*E_*QKV3_, wqh, E_, QKV3_);
        wsplit_kernel<<<dim3(E_/32, E_/32), dim3(32,8), 0, stream>>>(
            Wo + (size_t)i*E_*E_, woh, E_, E_);
        wsplit_kernel<<<dim3(FF_/32, E_/32), dim3(32,8), 0, stream>>>(
            W1 + (size_t)i*E_*FF_, w1h, E_, FF_);
        wsplit_kernel<<<dim3(E_/32, FF_/32), dim3(32,8), 0, stream>>>(
            W2 + (size_t)i*FF_*E_, w2h, FF_, E_);

        // e0 = LN1(e) -> f16 hi/lo planes
        ln_kernel<<<dim3(M_), dim3(256), 0, stream>>>(e, ln1g + i*E_, ln1b + i*E_, nullptr, actH, actL);
        // qkv = e0 @ Wqkv + bqkv -> scattered f16 q/k/vt planes
        gemm_kernel<0><<<dim3(QKV3_/128, M_/128), dim3(256), 0, stream>>>(
            actH, wqh, bqkv + i*QKV3_, nullptr, nullptr, nullptr,
            nullptr, nullptr, qh, kh, vt, M_, QKV3_, E_);
        // o = attention(q,k,v)
        attn_kernel<<<dim3(H_, B_, 4), dim3(256), 0, stream>>>(
            qh, kh, vt, rpos, padding, mu + i*H_, ga + i*H_, wv + i*H_, ob);
        // s = o @ Wo + bo + e0  -> f32 (aliases e)
        gemm_kernel<1><<<dim3(E_/128, M_/128), dim3(256), 0, stream>>>(
            ob, woh, bo + i*E_, actH, actL, nullptr,
            sbuf, nullptr, nullptr, nullptr, nullptr, M_, E_, E_);
        // e2 = LN2(s) -> f16 hi/lo planes
        ln_kernel<<<dim3(M_), dim3(256), 0, stream>>>(sbuf, ln2g + i*E_, ln2b + i*E_, nullptr, actH, actL);
        // h = relu(e2 @ W1 + b1) -> f16 (aliases qkv region)
        gemm_kernel<2><<<dim3(FF_/128, M_/128), dim3(256), 0, stream>>>(
            actH, w1h, b1 + i*FF_, nullptr, nullptr, nullptr,
            nullptr, hbuf, nullptr, nullptr, nullptr, M_, FF_, E_);
        // e = where(pad,0, h @ W2 + b2) + e2 -> f32 (same buffer as s)
        gemm_kernel<3><<<dim3(E_/128, M_/128), dim3(256), 0, stream>>>(
            hbuf, w2h, b2 + i*E_, actH, actL, padding,
            e, nullptr, nullptr, nullptr, nullptr, M_, E_, FF_);
    }

    ln_kernel<<<dim3(M_), dim3(256), 0, stream>>>(e, lnfg, lnfb, lnfo, nullptr, nullptr);
    mean_kernel<<<dim3(B_), dim3(256), 0, stream>>>(lnfo, meanb);
    out_kernel<<<dim3(B_), dim3(256), 0, stream>>>(meanb, Wout, bout, out);
}

// Round 5
// 4305.279 us; speedup vs baseline: 1.4128x; 1.4128x over previous
//
#include <hip/hip_runtime.h>
#include <cstdint>
#include <cstddef>

// ---------------- problem constants ----------------
#define B_    64
#define L_    256
#define E_    768
#define H_    12
#define DH_   64
#define D_    8
#define FF_   3072
#define QKV3_ 2304
#define M_    (B_*L_)   // 16384 token rows

typedef _Float16 f16;
typedef f16   f16x8  __attribute__((ext_vector_type(8)));
typedef float f32x4  __attribute__((ext_vector_type(4)));

// async global->LDS DMA, 16B per lane; LDS dest must be wave-uniform base + lane*16
__device__ __forceinline__ void gl_lds16(const void* g, void* l){
    __builtin_amdgcn_global_load_lds(
        (const __attribute__((address_space(1))) void*)g,
        (__attribute__((address_space(3))) void*)l, 16, 0, 0);
}

// ---------------- sentinel (ws too small diagnostic) ----------------
__global__ void sentinel_kernel(float* out, int n){
    int i = blockIdx.x*64 + threadIdx.x;
    if (i < n) out[i] = 1.0e6f;
}

// ---------------- embed gather ----------------
__global__ __launch_bounds__(256) void gather_kernel(
    const int* __restrict__ tok, const float* __restrict__ emb, float* __restrict__ e)
{
    const int idx = blockIdx.x*256 + threadIdx.x;
    const int row = idx / E_;
    const int d   = idx - row*E_;
    e[idx] = emb[(size_t)tok[row]*E_ + d];
}

// ---------------- weight transpose -> f16: W (K x N) -> (N x K) ----------------
__global__ void wsplit_kernel(const float* __restrict__ W, f16* __restrict__ Hh, int K, int N)
{
    __shared__ float tile[32][33];
    const int tx = threadIdx.x, ty = threadIdx.y;        // 32 x 8
#pragma unroll
    for (int i2 = 0; i2 < 4; ++i2){
        const int k = blockIdx.y*32 + ty + i2*8;
        const int n = blockIdx.x*32 + tx;
        tile[ty + i2*8][tx] = W[(size_t)k*N + n];
    }
    __syncthreads();
    const int k2 = blockIdx.y*32 + tx;
#pragma unroll
    for (int i2 = 0; i2 < 4; ++i2){
        const int n2 = blockIdx.x*32 + ty + i2*8;
        Hh[(size_t)n2*K + k2] = (f16)tile[tx][ty + i2*8];
    }
}

// ---------------- layernorm over E=768: optional f32 out + optional hi/lo f16 planes ----------------
__global__ __launch_bounds__(256) void ln_kernel(
    const float* __restrict__ x, const float* __restrict__ g, const float* __restrict__ bb,
    float* __restrict__ yF, f16* __restrict__ yH, f16* __restrict__ yL)
{
    __shared__ float red[256];
    const int row = blockIdx.x, tid = threadIdx.x;
    const float* xr = x + (size_t)row*E_;
    float v0 = xr[tid], v1 = xr[tid+256], v2 = xr[tid+512];
    red[tid] = v0 + v1 + v2;
    __syncthreads();
    for (int o = 128; o; o >>= 1){ if (tid < o) red[tid] += red[tid+o]; __syncthreads(); }
    const float mean = red[0] * (1.f/768.f);
    __syncthreads();
    const float d0 = v0-mean, d1 = v1-mean, d2 = v2-mean;
    red[tid] = d0*d0 + d1*d1 + d2*d2;
    __syncthreads();
    for (int o = 128; o; o >>= 1){ if (tid < o) red[tid] += red[tid+o]; __syncthreads(); }
    const float rstd = rsqrtf(red[0]*(1.f/768.f) + 1e-5f);
    const float dv[3] = {d0, d1, d2};
#pragma unroll
    for (int q = 0; q < 3; ++q){
        const int d = tid + q*256;
        const float y = dv[q]*rstd*g[d] + bb[d];
        const size_t idx = (size_t)row*E_ + d;
        if (yF) yF[idx] = y;
        if (yH){
            const f16 hi = (f16)y;
            yH[idx] = hi;
            yL[idx] = (f16)(y - (float)hi);
        }
    }
}

// ---------------- f16 GEMM: 128x128 tile, 3-buffer ring, ONE barrier/K-step ----------------
// C = A @ B^T + bias (+epilogue). A: Mn x Kn row-major f16. B^T: Nn x Kn row-major f16.
// R4 post-mortem decomposition: R2's counted-vmcnt schedule doubled per-wave
// efficiency (same 143us at half occupancy); its 64KB LDS cost the occupancy.
// This round combines both proven gains:
//  * 3-buffer ring (48KB) -> 3 blocks/CU (12 waves), __launch_bounds__(256,3)
//  * ONE raw s_barrier per K-step: {vmcnt(4) -> s_barrier -> STAGE(st+2) -> COMPUTE(st)}.
//    wait-before-barrier publishes buf[st] block-wide; the same barrier retires
//    step st-1's reads of buf[(st+2)%3] (3 distinct residues; max skew 1 barrier).
//  * R3/R4-verified involution LDS swizzle (conflicts 9.4M -> 0): chunk pos
//    j ^ ((row>>1)&3); gl_lds dest LINEAR, global source pre-swizzled (m104/m173).
//  * M-grouped XCD mapping (fixes R0-R4 bug: comment claimed same-M-per-XCD but
//    flat&7 varied with bx): by = (f&7) + 8*((f>>3)%ypg), bx = (f>>3)/ypg ->
//    all N-tiles of an M-panel on one XCD -> A-panel L2 hits.
// vmcnt: 4 gl_lds per thread per step, 2-step prefetch -> steady vmcnt(4), last 0.
// ns = Kn/32 divisible by 3 (K=768 -> 24, K=3072 -> 96).
// MODE 0 (QKV): scatter f16 -> qh/kh [b][h][256][64], vt [b][h][64][256]
// MODE 1 (Wo):  Cf = v + exH+exL (f32)
// MODE 2 (W1):  Cq = (f16)relu(v)
// MODE 3 (W2):  Cf = (pad?0:v) + exH+exL (f32)
template<int MODE>
__global__ __launch_bounds__(256, 3) void gemm_kernel(
    const f16* __restrict__ A, const f16* __restrict__ Bh,
    const float* __restrict__ bias,
    const f16* __restrict__ exH, const f16* __restrict__ exL,
    const unsigned char* __restrict__ pad,
    float* __restrict__ Cf, f16* __restrict__ Cq,
    f16* __restrict__ qh, f16* __restrict__ kh, f16* __restrict__ vt,
    int Mn, int Nn, int Kn)
{
    __shared__ f16 sA[3][128*32];    // 3 x 8KB
    __shared__ f16 sB[3][128*32];    // 3 x 8KB
    const int tid = threadIdx.x;
    const int w = tid >> 6, l = tid & 63;
    // ---- M-grouped XCD mapping: all N-tiles of one M-panel -> one XCD ----
    const int nt = gridDim.x;
    const int ypg = gridDim.y >> 3;                    // gridDim.y = 128 -> 16
    const int f = blockIdx.y * nt + blockIdx.x;        // hw dispatch order
    const int g = f >> 3;
    const int by = (f & 7) + 8 * (g % ypg);
    const int bx = g / ypg;
    const int m0 = by * 128, n0 = bx * 128;
    const int waveM = (w & 1) * 64, waveN = (w >> 1) * 64;
    const int fr = l & 15, fq = l >> 4;
    const int kswz = ((fq ^ ((fr >> 1) & 3)) << 3);    // swizzled k-chunk (f16 elems)
    f32x4 acc[4][4] = {};

    // ---- staging: thread t loads chunks {t, t+256} of A and of B.
    //      chunk q: row=q>>2, pos=q&3 holds global chunk (pos ^ ((row>>1)&3)) ----
    const int r0 = tid >> 2, j0 = tid & 3;
    const int r1 = r0 + 64;
    const int j0s = j0 ^ ((r0 >> 1) & 3);
    const int j1s = j0 ^ ((r1 >> 1) & 3);
    const f16* pa0 = A  + (size_t)(m0 + r0) * Kn + j0s*8;
    const f16* pa1 = A  + (size_t)(m0 + r1) * Kn + j1s*8;
    const f16* pb0 = Bh + (size_t)(n0 + r0) * Kn + j0s*8;
    const f16* pb1 = Bh + (size_t)(n0 + r1) * Kn + j1s*8;
    const int d0 = tid*8, d1 = tid*8 + 2048;           // linear LDS dests (f16 elems)

#define STAGE_(U, KK) do { \
        const size_t ko_ = (size_t)(KK) * 32; \
        gl_lds16(pa0 + ko_, &sA[U][d0]); \
        gl_lds16(pa1 + ko_, &sA[U][d1]); \
        gl_lds16(pb0 + ko_, &sB[U][d0]); \
        gl_lds16(pb1 + ko_, &sB[U][d1]); \
    } while(0)

#define COMPUTE_(U) do { \
        f16x8 fa[4], fb[4]; \
        _Pragma("unroll") \
        for (int m = 0; m < 4; ++m){ \
            fa[m] = *(const f16x8*)&sA[U][(waveM + m*16 + fr)*32 + kswz]; \
            fb[m] = *(const f16x8*)&sB[U][(waveN + m*16 + fr)*32 + kswz]; \
        } \
        __builtin_amdgcn_s_setprio(1); \
        _Pragma("unroll") \
        for (int m = 0; m < 4; ++m) \
        _Pragma("unroll") \
        for (int n = 0; n < 4; ++n) \
            acc[m][n] = __builtin_amdgcn_mfma_f32_16x16x32_f16(fa[m], fb[n], acc[m][n], 0,0,0); \
        __builtin_amdgcn_s_setprio(0); \
    } while(0)

#define WAITV4 asm volatile("s_waitcnt vmcnt(4)" ::: "memory")
#define WAITV0 asm volatile("s_waitcnt vmcnt(0)" ::: "memory")
#define BAR_   do { asm volatile("" ::: "memory"); __builtin_amdgcn_s_barrier(); asm volatile("" ::: "memory"); } while(0)

    const int ns = Kn >> 5;          // 24 or 96; divisible by 3
    STAGE_(0, 0);
    STAGE_(1, 1);
    for (int s = 0; s < ns; s += 3){
#pragma unroll
        for (int u = 0; u < 3; ++u){
            const int st = s + u;
            if (st + 1 < ns) WAITV4; else WAITV0;   // own buf[st] loads landed
            BAR_;                                   // publish buf[st]; free buf[(st+2)%3]
            if (st + 2 < ns) STAGE_((u + 2) % 3, st + 2);
            COMPUTE_(u);
        }
    }
#undef STAGE_
#undef COMPUTE_
#undef WAITV4
#undef WAITV0
#undef BAR_

    // epilogue: C/D layout col=lane&15, row=(lane>>4)*4+reg [m89/m91-verified]
#pragma unroll
    for (int jt = 0; jt < 4; ++jt){
        const int col = n0 + waveN + jt*16 + fr;
        const float bc = bias[col];
        int which = 0, hh = 0, dd = 0;
        if (MODE == 0){
            which = col / 768;
            const int hc = col - which*768;
            hh = hc >> 6; dd = hc & 63;
        }
#pragma unroll
        for (int it = 0; it < 4; ++it)
#pragma unroll
            for (int rg = 0; rg < 4; ++rg){
                const int row = m0 + waveM + it*16 + fq*4 + rg;
                float v = acc[it][jt][rg] + bc;
                if (MODE == 0){
                    const int bb2 = row >> 8, jj2 = row & 255;
                    const size_t bh = (size_t)bb2 * H_ + hh;
                    if (which == 0)      qh[(bh*256 + jj2)*64 + dd] = (f16)v;
                    else if (which == 1) kh[(bh*256 + jj2)*64 + dd] = (f16)v;
                    else                 vt[(bh*64 + dd)*256 + jj2] = (f16)v;
                } else {
                    const size_t idx = (size_t)row * Nn + col;
                    if (MODE == 1){
                        Cf[idx] = v + (float)exH[idx] + (float)exL[idx];
                    } else if (MODE == 2){
                        Cq[idx] = (f16)fmaxf(v, 0.f);
                    } else {
                        if (pad[row]) v = 0.f;
                        Cf[idx] = v + (float)exH[idx] + (float)exL[idx];
                    }
                }
            }
    }
}

// ---------------- MFMA flash attention: block per (b,h,p); p = 64-q-row quarter ----------------
__global__ __launch_bounds__(256, 4) void attn_kernel(
    const f16* __restrict__ qh, const f16* __restrict__ kh, const f16* __restrict__ vt,
    const float* __restrict__ rpos, const unsigned char* __restrict__ pad,
    const float* __restrict__ mu, const float* __restrict__ ga, const float* __restrict__ wv,
    f16* __restrict__ o)
{
    __shared__ f16 sK[64*72];        // K chunk [j][d], pad 72
    __shared__ f16 sV[64*72];        // Vt chunk [d][j], pad 72
    __shared__ f16 sP[4][16*72];     // per-wave P rows (A-layout), pad 72
    __shared__ float rx[256], ry[256], rz[256], pf[256];

    const int h = blockIdx.x, b = blockIdx.y, p = blockIdx.z;
    const int tid = threadIdx.x, w = tid >> 6, l = tid & 63;
    const int fr = l & 15, fq = l >> 4;
    const float muh = mu[h], gah = ga[h], wh = wv[h];
    const size_t bh = (size_t)b * H_ + h;
    const int rowbase = b * L_;

    rx[tid] = rpos[(size_t)(rowbase+tid)*3 + 0];
    ry[tid] = rpos[(size_t)(rowbase+tid)*3 + 1];
    rz[tid] = rpos[(size_t)(rowbase+tid)*3 + 2];
    pf[tid] = pad[rowbase+tid] ? 1.f : 0.f;

    f16x8 fQ[2];
    {
        const int r = p*64 + w*16 + fr;
        const f16* qp = qh + (bh*256 + r)*64 + fq*8;
        fQ[0] = *(const f16x8*)(qp);
        fQ[1] = *(const f16x8*)(qp + 32);
    }

    float m_[4], l_[4];
    f32x4 oacc[4] = {};
#pragma unroll
    for (int rg = 0; rg < 4; ++rg){ m_[rg] = -3.0e38f; l_[rg] = 0.f; }
    __syncthreads();

    for (int c = 0; c < 4; ++c){     // j-chunks of 64
        __syncthreads();
        {   // stage K chunk + Vt chunk (each 64x64 f16)
            const int e0 = tid*8, e1 = e0 + 2048;
            const int kr0 = e0 >> 6, kd0 = e0 & 63;
            const int kr1 = e1 >> 6, kd1 = e1 & 63;
            *(uint4*)&sK[kr0*72 + kd0] = *(const uint4*)&kh[(bh*256 + c*64 + kr0)*64 + kd0];
            *(uint4*)&sK[kr1*72 + kd1] = *(const uint4*)&kh[(bh*256 + c*64 + kr1)*64 + kd1];
            *(uint4*)&sV[kr0*72 + kd0] = *(const uint4*)&vt[(bh*64 + kr0)*256 + c*64 + kd0];
            *(uint4*)&sV[kr1*72 + kd1] = *(const uint4*)&vt[(bh*64 + kr1)*256 + c*64 + kd1];
        }
        __syncthreads();
        // ---- S = Q K^T ----
        f32x4 sacc[4] = {};
#pragma unroll
        for (int nt = 0; nt < 4; ++nt)
#pragma unroll
            for (int kf = 0; kf < 2; ++kf){
                const f16x8 fb = *(const f16x8*)&sK[(nt*16 + fr)*72 + kf*32 + fq*8];
                sacc[nt] = __builtin_amdgcn_mfma_f32_16x16x32_f16(fQ[kf], fb, sacc[nt], 0,0,0);
            }
        // ---- bias + mask ----
        float sv[4][4];
        float rmax[4] = {-3.0e38f, -3.0e38f, -3.0e38f, -3.0e38f};
        const int ibase = p*64 + w*16 + fq*4;
#pragma unroll
        for (int nt = 0; nt < 4; ++nt){
            const int j = c*64 + nt*16 + fr;
            const float jx = rx[j], jy = ry[j], jz = rz[j], jp = pf[j];
#pragma unroll
            for (int rg = 0; rg < 4; ++rg){
                const int i = ibase + rg;
                const float dx = rx[i]-jx, dy = ry[i]-jy, dz = rz[i]-jz;
                const float dist = sqrtf(dx*dx + dy*dy + dz*dz + 1e-12f);
                const float t = dist - muh;
                float s = sacc[nt][rg]*0.125f + wh*__expf(-gah*t*t);
                if ((j == i) | (pf[i] != 0.f) | (jp != 0.f)) s = -1e9f;
                sv[nt][rg] = s;
                rmax[rg] = fmaxf(rmax[rg], s);
            }
        }
        // ---- online softmax; P -> wave-private LDS (A layout) ----
#pragma unroll
        for (int rg = 0; rg < 4; ++rg){
#pragma unroll
            for (int off = 8; off >= 1; off >>= 1)
                rmax[rg] = fmaxf(rmax[rg], __shfl_xor(rmax[rg], off));
            const float mnew = fmaxf(m_[rg], rmax[rg]);
            const float alpha = __expf(m_[rg] - mnew);
            m_[rg] = mnew;
            l_[rg] *= alpha;
#pragma unroll
            for (int dt = 0; dt < 4; ++dt) oacc[dt][rg] *= alpha;
            float rs = 0.f;
#pragma unroll
            for (int nt = 0; nt < 4; ++nt){
                const float pv = __expf(sv[nt][rg] - mnew);
                sP[w][(fq*4 + rg)*72 + nt*16 + fr] = (f16)pv;
                rs += pv;
            }
#pragma unroll
            for (int off = 8; off >= 1; off >>= 1) rs += __shfl_xor(rs, off);
            l_[rg] += rs;
        }
        // ---- O += P @ V ----
#pragma unroll
        for (int kf = 0; kf < 2; ++kf){
            const f16x8 pa = *(const f16x8*)&sP[w][fr*72 + kf*32 + fq*8];
#pragma unroll
            for (int dt = 0; dt < 4; ++dt){
                const f16x8 vb = *(const f16x8*)&sV[(dt*16 + fr)*72 + kf*32 + fq*8];
                oacc[dt] = __builtin_amdgcn_mfma_f32_16x16x32_f16(pa, vb, oacc[dt], 0,0,0);
            }
        }
    }
    const int rglob = rowbase + p*64 + w*16 + fq*4;
#pragma unroll
    for (int rg = 0; rg < 4; ++rg){
        const float inv = 1.f / l_[rg];
#pragma unroll
        for (int dt = 0; dt < 4; ++dt)
            o[(size_t)(rglob + rg)*E_ + h*64 + dt*16 + fr] = (f16)(oacc[dt][rg]*inv);
    }
}

// ---------------- mean over L per (b, dim) ----------------
__global__ __launch_bounds__(256) void mean_kernel(const float* __restrict__ x, float* __restrict__ m)
{
    const int b = blockIdx.x, tid = threadIdx.x;
    const float* xb = x + (size_t)b*L_*E_;
#pragma unroll
    for (int q = 0; q < 3; ++q){
        const int d = tid + q*256;
        float s = 0.f;
        for (int l2 = 0; l2 < L_; ++l2) s += xb[(size_t)l2*E_ + d];
        m[b*E_ + d] = s * (1.f/(float)L_);
    }
}

// ---------------- final projection ----------------
__global__ __launch_bounds__(256) void out_kernel(
    const float* __restrict__ m, const float* __restrict__ Wout,
    const float* __restrict__ bout, float* __restrict__ out)
{
    __shared__ float red[256];
    const int b = blockIdx.x, tid = threadIdx.x;
    float s = 0.f;
#pragma unroll
    for (int q = 0; q < 3; ++q){ const int d = tid + q*256; s += m[b*E_ + d]*Wout[d]; }
    red[tid] = s;
    __syncthreads();
    for (int o = 128; o; o >>= 1){ if (tid < o) red[tid] += red[tid+o]; __syncthreads(); }
    if (tid == 0) out[b] = red[0] + bout[0];
}

// ---------------- host ----------------
extern "C" void kernel_launch(void* const* d_in, const int* in_sizes, int n_in,
                              void* d_out, int out_size, void* d_ws, size_t ws_size,
                              hipStream_t stream)
{
    const int*            tokens  = (const int*)d_in[0];
    const unsigned char*  padding = (const unsigned char*)d_in[1];
    const float*          rpos    = (const float*)d_in[2];
    const float*          embed   = (const float*)d_in[3];
    const float*          mu      = (const float*)d_in[4];
    const float*          ga      = (const float*)d_in[5];
    const float*          wv      = (const float*)d_in[6];
    const float*          Wqkv    = (const float*)d_in[7];
    const float*          bqkv    = (const float*)d_in[8];
    const float*          Wo      = (const float*)d_in[9];
    const float*          bo      = (const float*)d_in[10];
    const float*          ln1g    = (const float*)d_in[11];
    const float*          ln1b    = (const float*)d_in[12];
    const float*          W1      = (const float*)d_in[13];
    const float*          b1      = (const float*)d_in[14];
    const float*          W2      = (const float*)d_in[15];
    const float*          b2      = (const float*)d_in[16];
    const float*          ln2g    = (const float*)d_in[17];
    const float*          ln2b    = (const float*)d_in[18];
    const float*          lnfg    = (const float*)d_in[19];
    const float*          lnfb    = (const float*)d_in[20];
    const float*          Wout    = (const float*)d_in[21];
    const float*          bout    = (const float*)d_in[22];
    float* out = (float*)d_out;
    (void)in_sizes; (void)n_in;

    char* ws = (char*)d_ws;
    size_t off = 0;
    auto alloc = [&](size_t bytes)->char*{
        char* p = ws + off;
        off += (bytes + 255) & ~(size_t)255;
        return p;
    };
    const size_t PLANE = (size_t)M_*E_;                 // 12.58M elems
    float* e     = (float*)alloc(PLANE*4);              // residual; also s (Wo out) mid-layer
    char*  big   = alloc(PLANE*2*4);                    // qh|kh|vt|o ; later hbuf; later lnf f32
    f16*   actH  = (f16*)alloc(PLANE*2);                // LN planes (hi; GEMM A operand)
    f16*   actL  = (f16*)alloc(PLANE*2);                // LN planes (lo; residual reconstruction)
    f16*   wqh   = (f16*)alloc((size_t)E_*QKV3_*2);
    f16*   woh   = (f16*)alloc((size_t)E_*E_*2);
    f16*   w1h   = (f16*)alloc((size_t)E_*FF_*2);
    f16*   w2h   = (f16*)alloc((size_t)FF_*E_*2);
    float* meanb = (float*)alloc((size_t)B_*E_*4);
    const size_t required = off;

    if (ws_size < required){
        sentinel_kernel<<<dim3((out_size+63)/64), dim3(64), 0, stream>>>(out, out_size);
        return;
    }

    // aliases inside `big` (lifetimes disjoint):
    f16*   qh   = (f16*)big;                 // QKV gemm -> attn
    f16*   kh   = qh + PLANE;
    f16*   vt   = kh + PLANE;
    f16*   ob   = vt + PLANE;                // attn -> Wo gemm
    f16*   hbuf = (f16*)big;                 // W1 -> W2 (after qkv/o dead)
    float* lnfo = (float*)big;               // final LN out (first half)
    float* sbuf = e;                         // Wo-out f32 aliases residual (e dead LN1..MODE3)

    gather_kernel<<<dim3(M_*E_/256), dim3(256), 0, stream>>>(tokens, embed, e);

    for (int i = 0; i < D_; ++i){
        wsplit_kernel<<<dim3(QKV3_/32, E_/32), dim3(32,8), 0, stream>>>(
            Wqkv + (size_t)i*E_*QKV3_, wqh, E_, QKV3_);
        wsplit_kernel<<<dim3(E_/32, E_/32), dim3(32,8), 0, stream>>>(
            Wo + (size_t)i*E_*E_, woh, E_, E_);
        wsplit_kernel<<<dim3(FF_/32, E_/32), dim3(32,8), 0, stream>>>(
            W1 + (size_t)i*E_*FF_, w1h, E_, FF_);
        wsplit_kernel<<<dim3(E_/32, FF_/32), dim3(32,8), 0, stream>>>(
            W2 + (size_t)i*FF_*E_, w2h, FF_, E_);

        // e0 = LN1(e) -> f16 hi/lo planes
        ln_kernel<<<dim3(M_), dim3(256), 0, stream>>>(e, ln1g + i*E_, ln1b + i*E_, nullptr, actH, actL);
        // qkv = e0 @ Wqkv + bqkv -> scattered f16 q/k/vt planes
        gemm_kernel<0><<<dim3(QKV3_/128, M_/128), dim3(256), 0, stream>>>(
            actH, wqh, bqkv + i*QKV3_, nullptr, nullptr, nullptr,
            nullptr, nullptr, qh, kh, vt, M_, QKV3_, E_);
        // o = attention(q,k,v)
        attn_kernel<<<dim3(H_, B_, 4), dim3(256), 0, stream>>>(
            qh, kh, vt, rpos, padding, mu + i*H_, ga + i*H_, wv + i*H_, ob);
        // s = o @ Wo + bo + e0  -> f32 (aliases e)
        gemm_kernel<1><<<dim3(E_/128, M_/128), dim3(256), 0, stream>>>(
            ob, woh, bo + i*E_, actH, actL, nullptr,
            sbuf, nullptr, nullptr, nullptr, nullptr, M_, E_, E_);
        // e2 = LN2(s) -> f16 hi/lo planes
        ln_kernel<<<dim3(M_), dim3(256), 0, stream>>>(sbuf, ln2g + i*E_, ln2b + i*E_, nullptr, actH, actL);
        // h = relu(e2 @ W1 + b1) -> f16 (aliases qkv region)
        gemm_kernel<2><<<dim3(FF_/128, M_/128), dim3(256), 0, stream>>>(
            actH, w1h, b1 + i*FF_, nullptr, nullptr, nullptr,
            nullptr, hbuf, nullptr, nullptr, nullptr, M_, FF_, E_);
        // e = where(pad,0, h @ W2 + b2) + e2 -> f32 (same buffer as s)
        gemm_kernel<3><<<dim3(E_/128, M_/128), dim3(256), 0, stream>>>(
            hbuf, w2h, b2 + i*E_, actH, actL, padding,
            e, nullptr, nullptr, nullptr, nullptr, M_, E_, FF_);
    }

    ln_kernel<<<dim3(M_), dim3(256), 0, stream>>>(e, lnfg, lnfb, lnfo, nullptr, nullptr);
    mean_kernel<<<dim3(B_), dim3(256), 0, stream>>>(lnfo, meanb);
    out_kernel<<<dim3(B_), dim3(256), 0, stream>>>(meanb, Wout, bout, out);
}